// Round 4
// baseline (361.464 us; speedup 1.0000x reference)
//
#include <hip/hip_runtime.h>
#include <stdint.h>

#define N_NODES 50000
#define DD 256
#define SS 25

typedef unsigned short u16;
typedef __attribute__((ext_vector_type(8))) __bf16 bf16x8;
typedef __attribute__((ext_vector_type(4))) float f32x4;

__device__ __forceinline__ float bf2f(u16 u) {
    union { uint32_t i; float f; } c;
    c.i = ((uint32_t)u) << 16;
    return c.f;
}
__device__ __forceinline__ u16 f2bf(float f) {  // round-to-nearest-even
    union { float f; uint32_t i; } c;
    c.f = f;
    uint32_t r = c.i + 0x7fffu + ((c.i >> 16) & 1u);
    return (u16)(r >> 16);
}
__device__ __forceinline__ float u32_as_f(uint32_t u) {
    union { uint32_t i; float f; } c; c.i = u; return c.f;
}
__device__ __forceinline__ uint32_t f_as_u32(float f) {
    union { float f; uint32_t i; } c; c.f = f; return c.i;
}

__device__ __forceinline__ void gld16(void* lds, const void* g) {
    __builtin_amdgcn_global_load_lds(
        (const __attribute__((address_space(1))) uint32_t*)g,
        (__attribute__((address_space(3))) uint32_t*)lds, 16, 0, 0);
}

// ---- f32 -> bf16 elementwise (exact: grid*block*4 == n) ----
__global__ __launch_bounds__(256) void cvt_f32_bf16_k(const float4* __restrict__ in,
                                                      u16* __restrict__ out) {
    int i = blockIdx.x * 256 + threadIdx.x;
    float4 v = in[i];
    uint2 o;
    o.x = (uint32_t)f2bf(v.x) | ((uint32_t)f2bf(v.y) << 16);
    o.y = (uint32_t)f2bf(v.z) | ((uint32_t)f2bf(v.w) << 16);
    *reinterpret_cast<uint2*>(out + (size_t)i * 4) = o;
}

// ---- weight f32 [K][256] -> bf16 MFMA B-fragment layout ----
// out[((kt*16 + ct)*64 + lane)*8 + e] = W[kt*32 + (lane>>4)*8 + e][ct*16 + (lane&15)]
__global__ __launch_bounds__(256) void cvt_w_k(const float* __restrict__ W,
                                               u16* __restrict__ out, int KT) {
    int t = blockIdx.x * 256 + threadIdx.x;
    if (t >= KT * 16 * 64) return;
    int lane = t & 63;
    int ct = (t >> 6) & 15;
    int kt = t >> 10;
    int k0 = kt * 32 + (lane >> 4) * 8;
    int col = ct * 16 + (lane & 15);
    u16 r[8];
#pragma unroll
    for (int e = 0; e < 8; e++) r[e] = f2bf(W[(size_t)(k0 + e) * DD + col]);
    uint4 v;
    v.x = (uint32_t)r[0] | ((uint32_t)r[1] << 16);
    v.y = (uint32_t)r[2] | ((uint32_t)r[3] << 16);
    v.z = (uint32_t)r[4] | ((uint32_t)r[5] << 16);
    v.w = (uint32_t)r[6] | ((uint32_t)r[7] << 16);
    *reinterpret_cast<uint4*>(out + (size_t)t * 8) = v;
}

// ---- chunked gather + max-pool ----
// h layout: [8 chunks][N][32] bf16. Pass c touches a 3.2MB slice -> L2-resident.
// Block = 64 nodes, 4 waves; lane group of 4 owns one node's 8 bf16 of the chunk.
// Max on non-negative bf16 via hi/lo float trick (bit-exact, no unpack rounding).
__global__ __launch_bounds__(256) void gather_chunk_k(const u16* __restrict__ hc,
                                                      const int* __restrict__ idx,
                                                      u16* __restrict__ agg, int M) {
    __shared__ int soff[64 * SS];  // element offsets: idx*32
    const int tid = threadIdx.x;
    const int base = blockIdx.x * 64;
    for (int j = tid; j < 64 * SS; j += 256) {
        int n = base + j / SS;
        if (n >= M) n = M - 1;
        soff[j] = idx[(size_t)n * SS + (j % SS)] * 32;
    }
    __syncthreads();
    const int w = tid >> 6, lane = tid & 63;
    const int g = lane >> 2;       // node slot within wave
    const int q = lane & 3;        // quarter of the 32-elem chunk (8 bf16 = 16B)
    const int nl = w * 16 + g;     // node within block
    const int n = base + nl;
    const int* off = &soff[nl * SS];
#pragma unroll 1
    for (int c = 0; c < 8; ++c) {
        const u16* slice = hc + (size_t)c * ((size_t)N_NODES * 32);
        float mlo[4], mhi[4];
#pragma unroll
        for (int j = 0; j < 4; j++) { mlo[j] = 0.0f; mhi[j] = 0.0f; }
#pragma unroll
        for (int s = 0; s < SS; ++s) {
            const uint4 v = *reinterpret_cast<const uint4*>(slice + off[s] + q * 8);
            const uint32_t u[4] = {v.x, v.y, v.z, v.w};
#pragma unroll
            for (int j = 0; j < 4; j++) {
                mlo[j] = fmaxf(mlo[j], u32_as_f(u[j] << 16));
                mhi[j] = fmaxf(mhi[j], u32_as_f(u[j] & 0xffff0000u));
            }
        }
        if (n < M) {
            uint4 o;
            o.x = (f_as_u32(mlo[0]) >> 16) | (f_as_u32(mhi[0]) & 0xffff0000u);
            o.y = (f_as_u32(mlo[1]) >> 16) | (f_as_u32(mhi[1]) & 0xffff0000u);
            o.z = (f_as_u32(mlo[2]) >> 16) | (f_as_u32(mhi[2]) & 0xffff0000u);
            o.w = (f_as_u32(mlo[3]) >> 16) | (f_as_u32(mhi[3]) & 0xffff0000u);
            *reinterpret_cast<uint4*>(agg + (size_t)n * DD + c * 32 + q * 8) = o;
        }
    }
}

// ---- bf16 MFMA GEMM: out[M,256] = [A1 | A2][M, 32*KT] @ Bf + bias ----
// BM=64, BN=256 (single column block -> A read once), 8 waves, 2-phase dbuf,
// global_load_lds width 16. OMODE: 0 = bf16 row-major, 1 = bf16 chunked [8][N][32], 2 = f32.
template <int KT, bool RELU, int OMODE>
__global__ __launch_bounds__(512) void gemm64_k(const u16* __restrict__ A1,
                                                const u16* __restrict__ A2,
                                                const u16* __restrict__ Bf,
                                                const float* __restrict__ bias,
                                                u16* __restrict__ obf,
                                                float* __restrict__ of32, int M) {
    __shared__ u16 sX[2][2048];  // A tile: [lk 0..3][64 rows][8] per buf (4KB)
    __shared__ u16 sB[2][8192];  // B tile: 16 frags x 64 x 8 per buf (16KB)
    const int tid = threadIdx.x;
    const int lane = tid & 63;
    const int w = tid >> 6;  // 0..7
    const int row_base = blockIdx.x * 64;

    auto stageX = [&](int buf, int kt) {  // waves 0..3: k-subgroup = w
        if (w < 4) {
            int row = row_base + lane;
            if (row >= M) row = M - 1;
            const u16* src = (KT == 16 && kt >= 8)
                                 ? A2 + (size_t)row * DD + (kt - 8) * 32 + w * 8
                                 : A1 + (size_t)row * DD + kt * 32 + w * 8;
            gld16(&sX[buf][w * 512 + lane * 8], src);
        }
    };
    auto stageB = [&](int buf, int kt) {  // 2 col-frags per wave
#pragma unroll
        for (int j = 0; j < 2; ++j) {
            const int nl = w * 2 + j;
            gld16(&sB[buf][nl * 512 + lane * 8],
                  Bf + ((size_t)(kt * 16 + nl) * 64 + lane) * 8);
        }
    };

    const int lr = lane & 15, lk = lane >> 4;
    f32x4 acc[4][2] = {};

    auto compute = [&](int buf) {
        bf16x8 a[4], b[2];
#pragma unroll
        for (int m = 0; m < 4; m++)
            a[m] = *reinterpret_cast<const bf16x8*>(&sX[buf][lk * 512 + (m * 16 + lr) * 8]);
#pragma unroll
        for (int n = 0; n < 2; n++)
            b[n] = *reinterpret_cast<const bf16x8*>(&sB[buf][(w * 2 + n) * 512 + lane * 8]);
#pragma unroll
        for (int m = 0; m < 4; m++)
#pragma unroll
            for (int n = 0; n < 2; n++)
                acc[m][n] = __builtin_amdgcn_mfma_f32_16x16x32_bf16(a[m], b[n], acc[m][n], 0, 0, 0);
    };

    stageX(0, 0);
    stageB(0, 0);
    asm volatile("s_waitcnt vmcnt(0)" ::: "memory");
    __syncthreads();
    int buf = 0;
#pragma unroll
    for (int kt = 0; kt < KT - 1; ++kt) {
        stageX(buf ^ 1, kt + 1);
        stageB(buf ^ 1, kt + 1);
        compute(buf);
        asm volatile("s_waitcnt vmcnt(0)" ::: "memory");
        __syncthreads();
        buf ^= 1;
    }
    compute(buf);

    // epilogue: wave w owns cols [w*32, w*32+32)
#pragma unroll
    for (int n = 0; n < 2; n++) {
        const int col = w * 32 + n * 16 + lr;
        const float bz = bias[col];
#pragma unroll
        for (int m = 0; m < 4; m++) {
            const int r0 = row_base + m * 16 + lk * 4;
#pragma unroll
            for (int e = 0; e < 4; e++) {
                const int r = r0 + e;
                if (r < M) {
                    float v = acc[m][n][e] + bz;
                    if (RELU) v = fmaxf(v, 0.0f);
                    if (OMODE == 0)
                        obf[(size_t)r * DD + col] = f2bf(v);
                    else if (OMODE == 1)  // chunked h: chunk index == w
                        obf[((size_t)w * N_NODES + r) * 32 + n * 16 + lr] = f2bf(v);
                    else
                        of32[(size_t)r * DD + col] = v;
                }
            }
        }
    }
}

extern "C" void kernel_launch(void* const* d_in, const int* in_sizes, int n_in,
                              void* d_out, int out_size, void* d_ws, size_t ws_size,
                              hipStream_t stream) {
    const float* features = (const float*)d_in[0];
    const int* neigh = (const int*)d_in[1];
    const float* Wp0 = (const float*)d_in[2];
    const float* bp0 = (const float*)d_in[3];
    const float* Wfc0 = (const float*)d_in[4];
    const float* bfc0 = (const float*)d_in[5];
    const float* Wp1 = (const float*)d_in[6];
    const float* bp1 = (const float*)d_in[7];
    const float* Wfc1 = (const float*)d_in[8];
    const float* bfc1 = (const float*)d_in[9];
    float* out = (float*)d_out;

    const size_t ND = (size_t)N_NODES * DD;  // 12.8M
    u16* B0 = (u16*)d_ws;      // features bf16 -> later h1 (chunked)
    u16* B1 = B0 + ND;         // h0 (chunked) -> later O0 (row-major)
    u16* B2 = B1 + ND;         // agg
    u16* Wpb0 = B2 + ND;
    u16* Wfb0 = Wpb0 + 65536;
    u16* Wpb1 = Wfb0 + 131072;
    u16* Wfb1 = Wpb1 + 65536;

    cvt_w_k<<<32, 256, 0, stream>>>(Wp0, Wpb0, 8);
    cvt_w_k<<<64, 256, 0, stream>>>(Wfc0, Wfb0, 16);
    cvt_w_k<<<32, 256, 0, stream>>>(Wp1, Wpb1, 8);
    cvt_w_k<<<64, 256, 0, stream>>>(Wfc1, Wfb1, 16);
    cvt_f32_bf16_k<<<12500, 256, 0, stream>>>((const float4*)features, B0);

    const int gb = (N_NODES + 63) / 64;  // 782

    // ---- layer 0 ----
    gemm64_k<8, true, 1><<<gb, 512, 0, stream>>>(B0, nullptr, Wpb0, bp0, B1, nullptr, N_NODES);
    gather_chunk_k<<<gb, 256, 0, stream>>>(B1, neigh, B2, N_NODES);
    gemm64_k<16, true, 0><<<gb, 512, 0, stream>>>(B0, B2, Wfb0, bfc0, B1, nullptr, N_NODES);

    // ---- layer 1 ---- (B0 dead -> h1 chunked; B1 holds O0)
    gemm64_k<8, true, 1><<<gb, 512, 0, stream>>>(B1, nullptr, Wpb1, bp1, B0, nullptr, N_NODES);
    gather_chunk_k<<<gb, 256, 0, stream>>>(B0, neigh, B2, N_NODES);
    gemm64_k<16, false, 2><<<gb, 512, 0, stream>>>(B1, B2, Wfb1, bfc1, nullptr, out, N_NODES);
}